// Round 10
// baseline (522.226 us; speedup 1.0000x reference)
//
#include <hip/hip_runtime.h>
#include <hip/hip_bf16.h>

#define B_ 64
#define T_ 200
#define E_ 512
#define H_ 8
#define D_ 64

static constexpr float SCALE = 0.044194173824159216f;  // 512^-0.5

typedef __attribute__((ext_vector_type(8))) short bf16x8;
typedef __attribute__((ext_vector_type(4))) short bf16x4;
typedef __attribute__((ext_vector_type(4))) float f32x4;

static __device__ inline short f2bf(float f) {
    __hip_bfloat16 h = __float2bfloat16(f);
    return *(short*)&h;
}

// direct global->LDS DMA, 16B per lane, dest = lds_base + lane*16 (wave-uniform base)
static __device__ __forceinline__ void gload16(const short* g, short* l) {
    __builtin_amdgcn_global_load_lds(
        (const __attribute__((address_space(1))) void*)g,
        (__attribute__((address_space(3))) void*)l, 16, 0, 0);
}

#define FENCE asm volatile("" ::: "memory")
#define VMCNT(n) asm volatile("s_waitcnt vmcnt(" #n ")" ::: "memory")

// ---------------- f32 -> bf16 convert (x4 vectorized) ----------------
__global__ void conv_kernel(const float* __restrict__ in,
                            __hip_bfloat16* __restrict__ out, int n) {
    int i = (blockIdx.x * blockDim.x + threadIdx.x) * 4;
    if (i < n) {
        f32x4 v = *(const f32x4*)(in + i);
        bf16x4 r;
        #pragma unroll
        for (int j = 0; j < 4; ++j) r[j] = f2bf(v[j]);
        *(bf16x4*)((short*)out + i) = r;
    }
}

// ---------------- batched weight transpose+convert to (N,K) bf16 ----------------
// exact 1024-block 1D grid. blocks 0-511: cases 0-7 (512x512, 64 blocks each);
// 512-767: case 8 (N=2048); 768-1023: case 9 (K=2048).
// mode 0: in (K,N). mode 1: in (H,K,D), n=h*64+d.
__global__ __launch_bounds__(256) void wtall_kernel(
    const float* s0, const float* s1, const float* s2, const float* s3,
    const float* s4, const float* s5, const float* s6, const float* s7,
    const float* s8, const float* s9,
    __hip_bfloat16* d0, __hip_bfloat16* d1, __hip_bfloat16* d2,
    __hip_bfloat16* d3, __hip_bfloat16* d4, __hip_bfloat16* d5,
    __hip_bfloat16* d6, __hip_bfloat16* d7, __hip_bfloat16* d8,
    __hip_bfloat16* d9) {
    __shared__ float tile[64][65];
    int id = blockIdx.x;
    const float* in;
    __hip_bfloat16* out;
    int N = 512, K = 512, mode = 1, nb, kb;
    if (id < 512) {
        int z = id >> 6, r = id & 63;
        nb = r & 7; kb = r >> 3;
        switch (z) {
            case 0: in = s0; out = d0; break;
            case 1: in = s1; out = d1; break;
            case 2: in = s2; out = d2; break;
            case 3: in = s3; out = d3; mode = 0; break;
            case 4: in = s4; out = d4; break;
            case 5: in = s5; out = d5; break;
            case 6: in = s6; out = d6; break;
            default: in = s7; out = d7; mode = 0; break;
        }
    } else if (id < 768) {
        int r = id - 512;
        in = s8; out = d8; mode = 0; N = 2048;
        nb = r & 31; kb = r >> 5;
    } else {
        int r = id - 768;
        in = s9; out = d9; mode = 0; K = 2048;
        nb = r & 7; kb = r >> 3;
    }
    int n0 = nb * 64, k0 = kb * 64;
    int tx = threadIdx.x & 63, ty = threadIdx.x >> 6;  // ty 0..3
    #pragma unroll
    for (int i = 0; i < 16; ++i) {
        int k = k0 + ty + i * 4;
        float v;
        if (mode == 0) v = in[(size_t)k * N + n0 + tx];
        else { int h = n0 >> 6; v = in[((size_t)h * K + k) * 64 + tx]; }
        tile[ty + i * 4][tx] = v;
    }
    __syncthreads();
    #pragma unroll
    for (int i = 0; i < 16; ++i) {
        int n = ty + i * 4;
        out[(size_t)(n0 + n) * K + k0 + tx] = __float2bfloat16(tile[tx][n]);
    }
}

// ---------------- LayerNorm over E=512 -> bf16 out, one block per row ----------------
__global__ __launch_bounds__(256) void ln_kernel(const float* __restrict__ x,
                                                 const float* __restrict__ g,
                                                 const float* __restrict__ bta,
                                                 __hip_bfloat16* __restrict__ out) {
    __shared__ float red[4];
    int row = blockIdx.x;
    const float* xr = x + (size_t)row * E_;
    int tid = threadIdx.x;
    float v0 = xr[tid], v1 = xr[tid + 256];
    float s = v0 + v1;
    for (int off = 32; off; off >>= 1) s += __shfl_down(s, off, 64);
    if ((tid & 63) == 0) red[tid >> 6] = s;
    __syncthreads();
    float mu = (red[0] + red[1] + red[2] + red[3]) * (1.0f / E_);
    __syncthreads();
    float d0 = v0 - mu, d1 = v1 - mu;
    float sq = d0 * d0 + d1 * d1;
    for (int off = 32; off; off >>= 1) sq += __shfl_down(sq, off, 64);
    if ((tid & 63) == 0) red[tid >> 6] = sq;
    __syncthreads();
    float var = (red[0] + red[1] + red[2] + red[3]) * (1.0f / E_);
    float r = rsqrtf(var + 1e-5f);
    out[(size_t)row * E_ + tid] = __float2bfloat16(g[tid] * d0 * r + bta[tid]);
    out[(size_t)row * E_ + tid + 256] =
        __float2bfloat16(g[tid + 256] * d1 * r + bta[tid + 256]);
}

// ---- shared epilogue helper ----
template <int MSK, int RELU, int OM, int RES, int BIAS>
static __device__ __forceinline__ void epi_store(
    float val, int row, int col, int N, size_t wstep,
    const float* bias, const int* rmask, const float* resid, void* Cv) {
    if (BIAS) val += bias[col];
    if (MSK) {
        float mval = (rmask[row] != 0) ? 1.0f : 0.0f;
        if (MSK == 1) val *= mval;
        if (MSK == 2) { if (col < 1024) val *= mval; }
        if (MSK == 3) { if (col >= 1024) val *= mval; }
    }
    if (RELU) val = fmaxf(val, 0.0f);
    if (RES) val += resid[(size_t)row * N + col];
    if (OM == 0) {
        ((float*)Cv)[(size_t)row * N + col] = val;
    } else if (OM == 3) {
        int b_ = row / T_, t = row - b_ * T_;
        int which = col >> 9, cc = col & 511;
        int hh = cc >> 6, d = cc & 63;
        ((__hip_bfloat16*)Cv)[(size_t)which * wstep +
                              (((size_t)b_ * H_ + hh) * T_ + t) * D_ + d] =
            __float2bfloat16(val);
    } else if (OM == 4) {
        int b_ = row / T_, t = row - b_ * T_;
        int which = col >> 9, cc = col & 511;
        size_t off = (which == 1) ? 2 * wstep : (which == 2 ? wstep : 0);
        int hh = cc >> 6, d = cc & 63;
        ((__hip_bfloat16*)Cv)[off + (((size_t)b_ * H_ + hh) * T_ + t) * D_ + d] =
            __float2bfloat16(val);
    } else {
        ((__hip_bfloat16*)Cv)[(size_t)row * N + col] = __float2bfloat16(val);
    }
}

// ---- XCD-chunked bijective block swizzle (m204 formula) ----
static __device__ __forceinline__ void xcd_swz(int& by, int& bx) {
    int nwg = gridDim.x * gridDim.y;
    int flat = blockIdx.y * gridDim.x + blockIdx.x;
    int xcd = flat & 7, bix = flat >> 3;
    int qw = nwg >> 3, rw = nwg & 7;
    int nf = (xcd < rw ? xcd * (qw + 1) : rw * (qw + 1) + (xcd - rw) * qw) + bix;
    by = nf / gridDim.x;
    bx = nf - by * gridDim.x;
}

// ---------------- MFMA bf16 GEMM: 128x128 tile, BK=64, 2-phase ------------------
// For large-N shapes (>=1200 blocks). 64KB LDS -> 2 blocks/CU, counted vmcnt(8).
// Swizzle phys_unit = u ^ (row&7): conflict-free (verified 3.28M -> 0).
// MSK: 0 none, 1 all-col row mask, 2 cols<1024 masked, 3 cols>=1024 masked.
// OM: 0 f32 row-major, 2 bf16 row-major, 3 bf16 (B,H,T,D) routed (col>>9)*wstep,
//     4 same but {0->0,1->2w,2->w}; blocks with n0>=1024 read A2 (memory).
template <int MSK, int RELU, int OM, int RES, int BIAS>
__global__ __launch_bounds__(256) void mgemm_kernel(
    const short* __restrict__ A, const short* __restrict__ A2,
    const short* __restrict__ BT,
    const float* __restrict__ bias, const int* __restrict__ rmask,
    const float* __restrict__ resid, void* __restrict__ Cv,
    int M, int N, int K, size_t wstep) {
    __shared__ __align__(16) short As[2][128 * 64];
    __shared__ __align__(16) short Bs[2][128 * 64];
    int tid = threadIdx.x;
    int wave = tid >> 6, lane = tid & 63;
    int qq = lane >> 4, l15 = lane & 15;

    int by, bx;
    xcd_swz(by, bx);
    int m0 = by * 128, n0 = bx * 128;
    int wm = (wave & 1) * 64, wn = (wave >> 1) * 64;

    const short* Ap = A;
    if (OM == 4 && n0 >= 1024) Ap = A2;   // cross fused: k-panel reads memory

    int srow = lane >> 3;
    int scol = ((lane & 7) ^ srow) * 8;   // inverse-swizzled SOURCE
    const short* gA = Ap + (size_t)(m0 + wave * 32 + srow) * K + scol;
    const short* gB = BT + (size_t)(n0 + wave * 32 + srow) * K + scol;
    int lofs = wave * 32 * 64;
    size_t rstep = (size_t)8 * K;

    f32x4 acc[4][4] = {};

    auto STAGE = [&](int kt, int bufi) {
        int kk = kt << 6;
        #pragma unroll
        for (int c = 0; c < 4; ++c) {
            gload16(gA + kk + c * rstep, &As[bufi][lofs + c * 512]);
            gload16(gB + kk + c * rstep, &Bs[bufi][lofs + c * 512]);
        }
    };

    int nk = K >> 6;
    STAGE(0, 0);

    for (int it = 0; it < nk; ++it) {
        int cur = it & 1;
        if (it + 1 < nk) {
            STAGE(it + 1, cur ^ 1);
            VMCNT(8);
        } else {
            VMCNT(0);
        }
        __builtin_amdgcn_s_barrier();
        bf16x8 af[2][4], bfr[2][4];
        #pragma unroll
        for (int ks = 0; ks < 2; ++ks) {
            int pu = ((ks * 4 + qq) ^ (l15 & 7)) * 8;
            #pragma unroll
            for (int i = 0; i < 4; ++i)
                af[ks][i] = *(bf16x8*)(&As[cur][(wm + i * 16 + l15) * 64 + pu]);
            #pragma unroll
            for (int j = 0; j < 4; ++j)
                bfr[ks][j] = *(bf16x8*)(&Bs[cur][(wn + j * 16 + l15) * 64 + pu]);
        }
        #pragma unroll
        for (int ks = 0; ks < 2; ++ks)
            #pragma unroll
            for (int i = 0; i < 4; ++i)
                #pragma unroll
                for (int j = 0; j < 4; ++j)
                    acc[i][j] = __builtin_amdgcn_mfma_f32_16x16x32_bf16(
                        af[ks][i], bfr[ks][j], acc[i][j], 0, 0, 0);
        FENCE;
        __builtin_amdgcn_s_barrier();
    }

    #pragma unroll
    for (int i = 0; i < 4; ++i)
        #pragma unroll
        for (int r = 0; r < 4; ++r) {
            int row = m0 + wm + i * 16 + qq * 4 + r;
            #pragma unroll
            for (int j = 0; j < 4; ++j) {
                int col = n0 + wn + j * 16 + l15;
                epi_store<MSK, RELU, OM, RES, BIAS>(acc[i][j][r], row, col, N,
                                                    wstep, bias, rmask, resid, Cv);
            }
        }
}

// ---------------- MFMA bf16 GEMM: 64x128 tile, BK=64, 2-phase -------------------
// For N=512 shapes (grid would be only 400 blocks at 128x128 -> <1 block/CU,
// latency fully exposed). 64x128 gives 800 blocks AND 48KB LDS -> 3 blocks/CU:
// 2-3x the schedulable waves, cross-block overlap hides the barrier stalls.
// Wave w: rows wm=(w&1)*32 (2 frag rows), cols wn=(w>>1)*64 (4 frag cols).
// Staging: A 2 rounds (64 rows), B 4 rounds (128 rows); 6 gloads/K-step,
// counted vmcnt(6). Same u^(row&7) swizzle (row&7 == lane>>3 in every round).
template <int MSK, int RELU, int OM, int RES, int BIAS>
__global__ __launch_bounds__(256) void mgemm64_kernel(
    const short* __restrict__ A, const short* __restrict__ BT,
    const float* __restrict__ bias, const int* __restrict__ rmask,
    const float* __restrict__ resid, void* __restrict__ Cv,
    int M, int N, int K, size_t wstep) {
    __shared__ __align__(16) short As[2][64 * 64];
    __shared__ __align__(16) short Bs[2][128 * 64];
    int tid = threadIdx.x;
    int wave = tid >> 6, lane = tid & 63;
    int qq = lane >> 4, l15 = lane & 15;

    int by, bx;
    xcd_swz(by, bx);
    int m0 = by * 64, n0 = bx * 128;
    int wm = (wave & 1) * 32, wn = (wave >> 1) * 64;

    int srow = lane >> 3;                 // 0..7
    int scol = ((lane & 7) ^ srow) * 8;   // inverse-swizzled SOURCE
    // wave w stages rows {w*8+srow} of each 32-row round
    const short* gA = A + (size_t)(m0 + wave * 8 + srow) * K + scol;
    const short* gB = BT + (size_t)(n0 + wave * 8 + srow) * K + scol;
    size_t rstep = (size_t)32 * K;        // round stride (32 rows)

    f32x4 acc[2][4] = {};

    auto STAGE = [&](int kt, int bufi) {
        int kk = kt << 6;
        #pragma unroll
        for (int c = 0; c < 2; ++c)
            gload16(gA + kk + c * rstep, &As[bufi][(c * 32 + wave * 8) * 64]);
        #pragma unroll
        for (int c = 0; c < 4; ++c)
            gload16(gB + kk + c * rstep, &Bs[bufi][(c * 32 + wave * 8) * 64]);
    };

    int nk = K >> 6;
    STAGE(0, 0);

    for (int it = 0; it < nk; ++it) {
        int cur = it & 1;
        if (it + 1 < nk) {
            STAGE(it + 1, cur ^ 1);
            VMCNT(6);
        } else {
            VMCNT(0);
        }
        __builtin_amdgcn_s_barrier();
        bf16x8 af[2][2], bfr[2][4];
        #pragma unroll
        for (int ks = 0; ks < 2; ++ks) {
            int pu = ((ks * 4 + qq) ^ (l15 & 7)) * 8;
            #pragma unroll
            for (int i = 0; i < 2; ++i)
                af[ks][i] = *(bf16x8*)(&As[cur][(wm + i * 16 + l15) * 64 + pu]);
            #pragma unroll
            for (int j = 0; j < 4; ++j)
                bfr[ks][j] = *(bf16x8*)(&Bs[cur][(wn + j * 16 + l15) * 64 + pu]);
        }
        #pragma unroll
        for (int ks = 0; ks < 2; ++ks)
            #pragma unroll
            for (int i = 0; i < 2; ++i)
                #pragma unroll
                for (int j = 0; j < 4; ++j)
                    acc[i][j] = __builtin_amdgcn_mfma_f32_16x16x32_bf16(
                        af[ks][i], bfr[ks][j], acc[i][j], 0, 0, 0);
        FENCE;
        __builtin_amdgcn_s_barrier();
    }

    #pragma unroll
    for (int i = 0; i < 2; ++i)
        #pragma unroll
        for (int r = 0; r < 4; ++r) {
            int row = m0 + wm + i * 16 + qq * 4 + r;
            #pragma unroll
            for (int j = 0; j < 4; ++j) {
                int col = n0 + wn + j * 16 + l15;
                epi_store<MSK, RELU, OM, RES, BIAS>(acc[i][j][r], row, col, N,
                                                    wstep, bias, rmask, resid, Cv);
            }
        }
}

// ---------------- MFMA causal attention: one block per (b,h) --------------------
// q,k,v: (B,H,T,D) bf16.  o: (B,T,E) bf16, e = h*64+d.
// COMPILE-TIME causal skipping: per-wave static qt sets -> attn_tile<QT>
// instantiations; all guards constant-fold (straight-line, branch-free bodies).
// Balanced partition {12,5,3},{11,6,2},{10,7,1,0},{9,8,4}: 23/22/22/24 kt-tiles.
#define NQT 13

template <int QT>
static __device__ __forceinline__ void attn_tile(
    const short* __restrict__ qp, const short* __restrict__ Kf,
    const short* __restrict__ Vf, short* __restrict__ pb,
    __hip_bfloat16* __restrict__ o, int b, int h, int qq, int l15) {
    const int t0 = QT * 16;
    bf16x8 qf[2];
    #pragma unroll
    for (int ks = 0; ks < 2; ++ks)
        qf[ks] = *(const bf16x8*)(qp + (size_t)(t0 + l15) * 64 + ks * 32 + qq * 8);
    // ---- S = Q K^T over kt <= QT (static) ----
    f32x4 sc[QT + 1];
    #pragma unroll
    for (int kt = 0; kt <= QT; ++kt) {
        f32x4 a = {0.f, 0.f, 0.f, 0.f};
        bf16x8 kf0 = *(const bf16x8*)&Kf[((kt * 8 + qq) * 16 + l15) * 8];
        bf16x8 kf1 = *(const bf16x8*)&Kf[((kt * 8 + 4 + qq) * 16 + l15) * 8];
        a = __builtin_amdgcn_mfma_f32_16x16x32_bf16(qf[0], kf0, a, 0, 0, 0);
        a = __builtin_amdgcn_mfma_f32_16x16x32_bf16(qf[1], kf1, a, 0, 0, 0);
        sc[kt] = a;
    }
    #pragma unroll
    for (int kt = 0; kt <= QT; ++kt)
        #pragma unroll
        for (int r = 0; r < 4; ++r) {
            int col = kt * 16 + l15;
            int rowg = t0 + qq * 4 + r;
            sc[kt][r] = (col <= rowg) ? sc[kt][r] * SCALE : -1e30f;
        }
    float mx[4], sum[4], inv[4];
    #pragma unroll
    for (int r = 0; r < 4; ++r) {
        float m = -1e30f;
        #pragma unroll
        for (int kt = 0; kt <= QT; ++kt) m = fmaxf(m, sc[kt][r]);
        #pragma unroll
        for (int off = 1; off < 16; off <<= 1)
            m = fmaxf(m, __shfl_xor(m, off, 64));
        mx[r] = m;
    }
    #pragma unroll
    for (int r = 0; r < 4; ++r) sum[r] = 0.f;
    #pragma unroll
    for (int kt = 0; kt <= QT; ++kt)
        #pragma unroll
        for (int r = 0; r < 4; ++r) {
            float e = __expf(sc[kt][r] - mx[r]);
            sc[kt][r] = e;
            sum[r] += e;
        }
    #pragma unroll
    for (int r = 0; r < 4; ++r) {
        float s2 = sum[r];
        #pragma unroll
        for (int off = 1; off < 16; off <<= 1) s2 += __shfl_xor(s2, off, 64);
        inv[r] = 1.0f / s2;
    }
    // ---- O = P V over chunks 2c <= QT (static trip count) ----
    f32x4 oa[4] = {};
    constexpr int NC = QT / 2 + 1;
    #pragma unroll
    for (int c = 0; c < NC; ++c) {
        #pragma unroll
        for (int kt2 = 0; kt2 < 2; ++kt2) {
            int kt = c * 2 + kt2;
            int kti = (kt <= QT) ? kt : 0;
            int g = kt2 * 2 + (l15 >> 3);
            int jj = l15 & 7;
            #pragma unroll
            for (int r = 0; r < 4; ++r) {
                float val = (kt <= QT) ? sc[kti][r] : 0.0f;
                pb[(g * 16 + qq * 4 + r) * 8 + jj] = f2bf(val);
            }
        }
        bf16x8 pf = *(const bf16x8*)&pb[(qq * 16 + l15) * 8];
        #pragma unroll
        for (int nt = 0; nt < 4; ++nt) {
            bf16x8 vf = *(const bf16x8*)&Vf[((nt * 28 + c * 4 + qq) * 16 + l15) * 8];
            oa[nt] = __builtin_amdgcn_mfma_f32_16x16x32_bf16(pf, vf, oa[nt], 0, 0, 0);
        }
    }
    #pragma unroll
    for (int nt = 0; nt < 4; ++nt)
        #pragma unroll
        for (int r = 0; r < 4; ++r) {
            int t = t0 + qq * 4 + r;
            if (QT < 12 || t < T_) {
                int d = nt * 16 + l15;
                o[((size_t)b * T_ + t) * E_ + h * D_ + d] =
                    __float2bfloat16(oa[nt][r] * inv[r]);
            }
        }
}

__global__ __launch_bounds__(256) void fattn_kernel(const short* __restrict__ q,
                                                    const short* __restrict__ k,
                                                    const short* __restrict__ v,
                                                    __hip_bfloat16* __restrict__ o) {
    __shared__ __align__(16) short Kf[NQT * 8 * 16 * 8];
    __shared__ __align__(16) short Vf[4 * 28 * 16 * 8];
    __shared__ __align__(16) short Pb[4 * 512];

    int tid = threadIdx.x;
    int wave = tid >> 6, lane = tid & 63;
    int qq = lane >> 4, l15 = lane & 15;
    int bh = blockIdx.x;
    int b = bh >> 3, h = bh & 7;

    const short* kp = k + (size_t)bh * T_ * D_;
    const short* vp = v + (size_t)bh * T_ * D_;
    const short* qp = q + (size_t)bh * T_ * D_;

    for (int idx = tid; idx < 8 * 208; idx += 256) {
        int g = idx / 208, s = idx - g * 208;
        int kt = s >> 4, l = s & 15;
        bf16x8 val;
        if (s < 200) {
            val = *(const bf16x8*)(kp + (size_t)s * 64 + g * 8);
        } else {
            #pragma unroll
            for (int j = 0; j < 8; ++j) val[j] = 0;
        }
        *(bf16x8*)&Kf[((kt * 8 + g) * 16 + l) * 8] = val;
    }
    for (int idx = tid; idx < 28 * 64; idx += 256) {
        int g = idx >> 6, d = idx & 63;
        int nt = d >> 4, dl = d & 15;
        bf16x8 val;
        if (g < 25) {
            #pragma unroll
            for (int j = 0; j < 8; ++j) val[j] = vp[(g * 8 + j) * 64 + d];
        } else {
            #pragma unroll
            for (int j = 0; j < 8; ++j) val[j] = 0;
        }
        *(bf16x8*)&Vf[((nt * 28 + g) * 16 + dl) * 8] = val;
    }
    __syncthreads();

    short* pb = &Pb[wave * 512];

    if (wave == 0) {
        attn_tile<12>(qp, Kf, Vf, pb, o, b, h, qq, l15);
        attn_tile<5>(qp, Kf, Vf, pb, o, b, h, qq, l15);
        attn_tile<3>(qp, Kf, Vf, pb, o, b, h, qq, l15);
    } else if (wave == 1) {
        attn_tile<11>(qp, Kf, Vf, pb, o, b, h, qq, l15);
        attn_tile<6>(qp, Kf, Vf, pb, o, b, h, qq, l15);
        attn_tile<2>(qp, Kf, Vf, pb, o, b, h, qq, l15);
    } else if (wave == 2) {
        attn_tile<10>(qp, Kf, Vf, pb, o, b, h, qq, l15);
        attn_tile<7>(qp, Kf, Vf, pb, o, b, h, qq, l15);
        attn_tile<1>(qp, Kf, Vf, pb, o, b, h, qq, l15);
        attn_tile<0>(qp, Kf, Vf, pb, o, b, h, qq, l15);
    } else {
        attn_tile<9>(qp, Kf, Vf, pb, o, b, h, qq, l15);
        attn_tile<8>(qp, Kf, Vf, pb, o, b, h, qq, l15);
        attn_tile<4>(qp, Kf, Vf, pb, o, b, h, qq, l15);
    }
}

extern "C" void kernel_launch(void* const* d_in, const int* in_sizes, int n_in,
                              void* d_out, int out_size, void* d_ws, size_t ws_size,
                              hipStream_t stream) {
    const float* idx    = (const float*)d_in[0];
    const float* memory = (const float*)d_in[1];
    const int* src_mask  = (const int*)d_in[2];
    const int* pred_mask = (const int*)d_in[3];
    const float* sa_wq = (const float*)d_in[4];
    const float* sa_wk = (const float*)d_in[5];
    const float* sa_wv = (const float*)d_in[6];
    const float* sa_wo = (const float*)d_in[7];
    const float* sa_bo = (const float*)d_in[8];
    const float* ca_wq = (const float*)d_in[9];
    const float* ca_wk = (const float*)d_in[10];
    const float* ca_wv = (const float*)d_in[11];
    const float* ca_wo = (const float*)d_in[12];
    const float* ca_bo = (const float*)d_in[13];
    const float* f_w1  = (const float*)d_in[14];
    const float* f_b1  = (const float*)d_in[15];
    const float* f_w2  = (const float*)d_in[16];
    const float* f_b2  = (const float*)d_in[17];
    const float* ln1_g = (const float*)d_in[18];
    const float* ln1_b = (const float*)d_in[19];
    const float* ln2_g = (const float*)d_in[20];
    const float* ln2_b = (const float*)d_in[21];
    const float* ln3_g = (const float*)d_in[22];
    const float* ln3_b = (const float*)d_in[23];
    float* out = (float*)d_out;

    const size_t BTE = (size_t)B_ * T_ * E_;  // 6,553,600
    const size_t EE = (size_t)E_ * E_;        // 262,144

    char* p = (char*)d_ws;
    short* qb = (short*)p;            p += BTE * 2;   // bf16 QKV buffers, consecutive
    short* kb = (short*)p;            p += BTE * 2;
    short* vb = (short*)p;            p += BTE * 2;
    float* x1 = (float*)p;            p += BTE * 4;
    __hip_bfloat16* h_bf   = (__hip_bfloat16*)p; p += BTE * 2;
    __hip_bfloat16* o_bf   = (__hip_bfloat16*)p; p += BTE * 2;
    __hip_bfloat16* mem_bf = (__hip_bfloat16*)p; p += BTE * 2;
    __hip_bfloat16* w_qkv_s = (__hip_bfloat16*)p; p += 3 * EE * 2;  // sa q|k|v
    __hip_bfloat16* w_o_s   = (__hip_bfloat16*)p; p += EE * 2;
    __hip_bfloat16* w_qvk_c = (__hip_bfloat16*)p; p += 3 * EE * 2;  // ca q|v|k
    __hip_bfloat16* w_o_c   = (__hip_bfloat16*)p; p += EE * 2;
    __hip_bfloat16* w1T     = (__hip_bfloat16*)p; p += EE * 4 * 2;  // (2048,512)
    __hip_bfloat16* w2T     = (__hip_bfloat16*)p; p += EE * 4 * 2;  // (512,2048)
    short* ff_bf = qb;  // aliases qb..x1 region (dead by FFN)

    const int M = B_ * T_;  // 12800
    dim3 blk(256);
    dim3 g512(E_ / 128, M / 64);        // 64x128 tiles: (4, 200) = 800 blocks
    dim3 g1536(12, M / 128);            // fused q|k|v and q|v|k (1200 blocks)
    dim3 g2048(16, M / 128);            // FFN up (1600 blocks)

    // ---- prep: batched weight transposes (exact grid) + memory convert ----
    wtall_kernel<<<1024, blk, 0, stream>>>(
        sa_wq, sa_wk, sa_wv, sa_wo, ca_wq, ca_wv, ca_wk, ca_wo, f_w1, f_w2,
        w_qkv_s, w_qkv_s + EE, w_qkv_s + 2 * EE, w_o_s,
        w_qvk_c, w_qvk_c + EE, w_qvk_c + 2 * EE, w_o_c, w1T, w2T);
    conv_kernel<<<((int)(BTE / 4) + 255) / 256, 256, 0, stream>>>(memory, mem_bf,
                                                                  (int)BTE);

    // ---- self-attention block ----
    ln_kernel<<<M, 256, 0, stream>>>(idx, ln1_g, ln1_b, h_bf);
    // fused QKV: cols 0-511 -> qb (masked), 512-1023 -> kb (masked), 1024-1535 -> vb
    mgemm_kernel<2,0,3,0,0><<<g1536, blk, 0, stream>>>(
        (const short*)h_bf, nullptr, (const short*)w_qkv_s, nullptr, pred_mask,
        nullptr, qb, M, 3 * E_, E_, BTE);
    fattn_kernel<<<B_ * H_, 256, 0, stream>>>(qb, kb, vb, o_bf);
    mgemm64_kernel<0,0,0,1,1><<<g512, blk, 0, stream>>>(
        (const short*)o_bf, (const short*)w_o_s, sa_bo, nullptr, idx, x1,
        M, E_, E_, 0);

    // ---- cross-attention block ----
    ln_kernel<<<M, 256, 0, stream>>>(x1, ln2_g, ln2_b, h_bf);
    // fused q|v|k: cols 0-511 (A=h) -> qb, 512-1023 (A=h) -> vb,
    //              1024-1535 (A=mem, src-masked) -> kb
    mgemm_kernel<3,0,4,0,0><<<g1536, blk, 0, stream>>>(
        (const short*)h_bf, (const short*)mem_bf, (const short*)w_qvk_c, nullptr,
        src_mask, nullptr, qb, M, 3 * E_, E_, BTE);
    fattn_kernel<<<B_ * H_, 256, 0, stream>>>(qb, kb, vb, o_bf);
    mgemm64_kernel<0,0,0,1,1><<<g512, blk, 0, stream>>>(
        (const short*)o_bf, (const short*)w_o_c, ca_bo, nullptr, x1, out,
        M, E_, E_, 0);

    // ---- feed-forward block ----
    ln_kernel<<<M, 256, 0, stream>>>(out, ln3_g, ln3_b, h_bf);
    mgemm_kernel<0,1,2,0,1><<<g2048, blk, 0, stream>>>(
        (const short*)h_bf, nullptr, (const short*)w1T, f_b1, nullptr, nullptr,
        ff_bf, M, 4 * E_, E_, 0);
    mgemm64_kernel<0,0,0,1,1><<<g512, blk, 0, stream>>>(
        (const short*)ff_bf, (const short*)w2T, f_b2, nullptr, out, out,
        M, E_, 4 * E_, 0);
}

// Round 11
// 433.412 us; speedup vs baseline: 1.2049x; 1.2049x over previous
//
#include <hip/hip_runtime.h>
#include <hip/hip_bf16.h>

#define B_ 64
#define T_ 200
#define E_ 512
#define H_ 8
#define D_ 64

static constexpr float SCALE = 0.044194173824159216f;  // 512^-0.5

typedef __attribute__((ext_vector_type(8))) short bf16x8;
typedef __attribute__((ext_vector_type(4))) short bf16x4;
typedef __attribute__((ext_vector_type(4))) float f32x4;

static __device__ inline short f2bf(float f) {
    __hip_bfloat16 h = __float2bfloat16(f);
    return *(short*)&h;
}

// direct global->LDS DMA, 16B per lane, dest = lds_base + lane*16 (wave-uniform base)
static __device__ __forceinline__ void gload16(const short* g, short* l) {
    __builtin_amdgcn_global_load_lds(
        (const __attribute__((address_space(1))) void*)g,
        (__attribute__((address_space(3))) void*)l, 16, 0, 0);
}

// ---------------- f32 -> bf16 convert (x4 vectorized) ----------------
__global__ void conv_kernel(const float* __restrict__ in,
                            __hip_bfloat16* __restrict__ out, int n) {
    int i = (blockIdx.x * blockDim.x + threadIdx.x) * 4;
    if (i < n) {
        f32x4 v = *(const f32x4*)(in + i);
        bf16x4 r;
        #pragma unroll
        for (int j = 0; j < 4; ++j) r[j] = f2bf(v[j]);
        *(bf16x4*)((short*)out + i) = r;
    }
}

// ---------------- weight transpose+convert to (N,K) bf16, LDS-tiled ----------------
// MODE 0: input (K,N) f32.  MODE 1: input (H,K,D) f32, N = H*64, n = h*64+d.
// 64x64 tiles, grid (N/64, K/64), 256 threads. Coalesced read AND write.
template <int MODE>
__global__ __launch_bounds__(256) void wt_kernel(const float* __restrict__ in,
                                                 __hip_bfloat16* __restrict__ out,
                                                 int N, int K) {
    __shared__ float tile[64][65];
    int n0 = blockIdx.x * 64, k0 = blockIdx.y * 64;
    int tx = threadIdx.x & 63, ty = threadIdx.x >> 6;  // ty 0..3
    #pragma unroll
    for (int i = 0; i < 16; ++i) {
        int k = k0 + ty + i * 4;
        float v;
        if (MODE == 0) {
            v = in[(size_t)k * N + n0 + tx];
        } else {
            int h = n0 >> 6;  // tile is n-aligned to 64 and D=64 -> h uniform
            v = in[((size_t)h * K + k) * 64 + tx];
        }
        tile[ty + i * 4][tx] = v;
    }
    __syncthreads();
    #pragma unroll
    for (int i = 0; i < 16; ++i) {
        int n = ty + i * 4;
        out[(size_t)(n0 + n) * K + k0 + tx] = __float2bfloat16(tile[tx][n]);
    }
}

// ---------------- LayerNorm over E=512 -> bf16 out, one block per row ----------------
__global__ __launch_bounds__(256) void ln_kernel(const float* __restrict__ x,
                                                 const float* __restrict__ g,
                                                 const float* __restrict__ bta,
                                                 __hip_bfloat16* __restrict__ out) {
    __shared__ float red[4];
    int row = blockIdx.x;
    const float* xr = x + (size_t)row * E_;
    int tid = threadIdx.x;
    float v0 = xr[tid], v1 = xr[tid + 256];
    float s = v0 + v1;
    for (int off = 32; off; off >>= 1) s += __shfl_down(s, off, 64);
    if ((tid & 63) == 0) red[tid >> 6] = s;
    __syncthreads();
    float mu = (red[0] + red[1] + red[2] + red[3]) * (1.0f / E_);
    __syncthreads();
    float d0 = v0 - mu, d1 = v1 - mu;
    float sq = d0 * d0 + d1 * d1;
    for (int off = 32; off; off >>= 1) sq += __shfl_down(sq, off, 64);
    if ((tid & 63) == 0) red[tid >> 6] = sq;
    __syncthreads();
    float var = (red[0] + red[1] + red[2] + red[3]) * (1.0f / E_);
    float r = rsqrtf(var + 1e-5f);
    out[(size_t)row * E_ + tid] = __float2bfloat16(g[tid] * d0 * r + bta[tid]);
    out[(size_t)row * E_ + tid + 256] =
        __float2bfloat16(g[tid + 256] * d1 * r + bta[tid + 256]);
}

// ---------------- MFMA bf16 GEMM: C(MxN) = A(MxK) * BT(NxK)^T + epilogue --------
// 128x128 tile, BK=64, 256 threads (4 waves, each 64x64 via 4x4x2 of 16x16x32).
// BK=64 halves barrier/vmcnt events per FLOP vs BK=32 (the 2-phase structural
// overhead, m233). 2 LDS buffers (64KB), 1 K-tile prefetch, counted vmcnt(8).
// Rows are 128B = 8 x 16B units; swizzle phys_unit = logical ^ (row&7):
// frag reads 2-way max (free); gload source pre-swizzled by (lane&7)^(lane>>3).
// XCD-aware bijective block swizzle for A/B-panel L2 reuse.
// MSK: 0=none, 1=all cols row-masked, 2=cols<1024 masked (self QKV),
//      3=cols>=1024 masked (cross fused: k only).
// OM: 0=f32 row-major, 2=bf16 row-major,
//     3=bf16 (B,H,T,D) routed (col>>9)*wstep          (self q|k|v),
//     4=bf16 (B,H,T,D) routed {0->0, 1->2w, 2->w}     (cross q|v|k),
//        blocks with n0>=1024 read A2 (memory) instead of A.
template <int MSK, int RELU, int OM, int RES, int BIAS>
__global__ __launch_bounds__(256) void mgemm_kernel(
    const short* __restrict__ A, const short* __restrict__ A2,
    const short* __restrict__ BT,
    const float* __restrict__ bias, const int* __restrict__ rmask,
    const float* __restrict__ resid, void* __restrict__ Cv,
    int M, int N, int K, size_t wstep) {
    __shared__ __align__(16) short As[2][128 * 64];
    __shared__ __align__(16) short Bs[2][128 * 64];
    int tid = threadIdx.x;
    int wave = tid >> 6, lane = tid & 63;
    int qq = lane >> 4, l15 = lane & 15;

    // ---- XCD-chunked bijective block swizzle (m204 formula) ----
    int nwg = gridDim.x * gridDim.y;
    int flat = blockIdx.y * gridDim.x + blockIdx.x;
    int xcd = flat & 7, bix = flat >> 3;
    int qw = nwg >> 3, rw = nwg & 7;
    int nf = (xcd < rw ? xcd * (qw + 1) : rw * (qw + 1) + (xcd - rw) * qw) + bix;
    int by = nf / gridDim.x, bx = nf - by * gridDim.x;
    int m0 = by * 128, n0 = bx * 128;
    int wm = (wave & 1) * 64, wn = (wave >> 1) * 64;

    const short* Ap = A;
    if (OM == 4 && n0 >= 1024) Ap = A2;   // cross fused: k-panel comes from memory

    // staging: wave stages rows [wave*32, wave*32+32), 4 chunks of 8 rows per array.
    // lane -> (row_off = lane>>3, unit = lane&7); source unit = (lane&7)^(lane>>3).
    int srow = lane >> 3;
    int scol = ((lane & 7) ^ srow) * 8;   // inverse-swizzled SOURCE (elements)
    const short* gA = Ap + (size_t)(m0 + wave * 32 + srow) * K + scol;
    const short* gB = BT + (size_t)(n0 + wave * 32 + srow) * K + scol;
    int lofs = wave * 32 * 64;            // wave's 32-row slab (shorts)
    size_t rstep = (size_t)8 * K;         // 8 rows per chunk; (r&7) invariant

    f32x4 acc[4][4] = {};

    auto STAGE = [&](int kt, int bufi) {
        int kk = kt << 6;
        #pragma unroll
        for (int c = 0; c < 4; ++c) {
            gload16(gA + kk + c * rstep, &As[bufi][lofs + c * 512]);
            gload16(gB + kk + c * rstep, &Bs[bufi][lofs + c * 512]);
        }
    };

    int nk = K >> 6;  // 8 (K=512) or 32 (K=2048)
    STAGE(0, 0);

    for (int it = 0; it < nk; ++it) {
        int cur = it & 1;
        if (it + 1 < nk) {
            STAGE(it + 1, cur ^ 1);
            asm volatile("s_waitcnt vmcnt(8)" ::: "memory");  // tile it's 8 landed
        } else {
            asm volatile("s_waitcnt vmcnt(0)" ::: "memory");
        }
        __builtin_amdgcn_s_barrier();
        // fragment reads: logical unit = ks*4+qq, phys = (ks*4+qq)^(l15&7)
        bf16x8 af[2][4], bfr[2][4];
        #pragma unroll
        for (int ks = 0; ks < 2; ++ks) {
            int pu = ((ks * 4 + qq) ^ (l15 & 7)) * 8;
            #pragma unroll
            for (int i = 0; i < 4; ++i)
                af[ks][i] = *(bf16x8*)(&As[cur][(wm + i * 16 + l15) * 64 + pu]);
            #pragma unroll
            for (int j = 0; j < 4; ++j)
                bfr[ks][j] = *(bf16x8*)(&Bs[cur][(wn + j * 16 + l15) * 64 + pu]);
        }
        #pragma unroll
        for (int ks = 0; ks < 2; ++ks)
            #pragma unroll
            for (int i = 0; i < 4; ++i)
                #pragma unroll
                for (int j = 0; j < 4; ++j)
                    acc[i][j] = __builtin_amdgcn_mfma_f32_16x16x32_bf16(
                        af[ks][i], bfr[ks][j], acc[i][j], 0, 0, 0);
        asm volatile("" ::: "memory");
        __builtin_amdgcn_s_barrier();  // cur fully consumed; safe to restage
    }

    #pragma unroll
    for (int i = 0; i < 4; ++i) {
        #pragma unroll
        for (int r = 0; r < 4; ++r) {
            int row = m0 + wm + i * 16 + qq * 4 + r;
            float mval = 1.0f;
            if (MSK) mval = (rmask[row] != 0) ? 1.0f : 0.0f;
            #pragma unroll
            for (int j = 0; j < 4; ++j) {
                int col = n0 + wn + j * 16 + l15;
                float val = acc[i][j][r];
                if (BIAS) val += bias[col];
                if (MSK == 1) val *= mval;
                if (MSK == 2) { if (col < 1024) val *= mval; }
                if (MSK == 3) { if (col >= 1024) val *= mval; }
                if (RES) val += resid[(size_t)row * N + col];
                if (RELU) val = fmaxf(val, 0.0f);
                if (OM == 0) {
                    ((float*)Cv)[(size_t)row * N + col] = val;
                } else if (OM == 3) {
                    int b_ = row / T_, t = row - b_ * T_;
                    int which = col >> 9, cc = col & 511;
                    int hh = cc >> 6, d = cc & 63;
                    ((__hip_bfloat16*)Cv)[(size_t)which * wstep +
                                          (((size_t)b_ * H_ + hh) * T_ + t) * D_ + d] =
                        __float2bfloat16(val);
                } else if (OM == 4) {
                    int b_ = row / T_, t = row - b_ * T_;
                    int which = col >> 9, cc = col & 511;
                    size_t off = (which == 1) ? 2 * wstep : (which == 2 ? wstep : 0);
                    int hh = cc >> 6, d = cc & 63;
                    ((__hip_bfloat16*)Cv)[off +
                                          (((size_t)b_ * H_ + hh) * T_ + t) * D_ + d] =
                        __float2bfloat16(val);
                } else {
                    ((__hip_bfloat16*)Cv)[(size_t)row * N + col] =
                        __float2bfloat16(val);
                }
            }
        }
    }
}

// ---------------- MFMA causal attention: one block per (b,h) --------------------
// q,k,v: (B,H,T,D) bf16.  o: (B,T,E) bf16, e = h*64+d.
// 13 Q-row tiles of 16 (T=200 padded to 208); K padded to 208, V^T to 224.
// LDS layouts are MFMA-fragment-contiguous: frag reads are 256B bursts, no conflicts.
#define NQT 13
__global__ __launch_bounds__(256) void fattn_kernel(const short* __restrict__ q,
                                                    const short* __restrict__ k,
                                                    const short* __restrict__ v,
                                                    __hip_bfloat16* __restrict__ o) {
    // Kf: [kt 13][g 8][l15 16][j 8]  (g = d/8)                 26,624 B
    // Vf: [nt 4][g 28][l15 16][j 8]  (g = s/8, l15 = d%16)     28,672 B
    // Pb: per-wave P chunk [g 4][m 16][j 8]                     4 * 1,024 B
    __shared__ __align__(16) short Kf[NQT * 8 * 16 * 8];
    __shared__ __align__(16) short Vf[4 * 28 * 16 * 8];
    __shared__ __align__(16) short Pb[4 * 512];

    int tid = threadIdx.x;
    int wave = tid >> 6, lane = tid & 63;
    int qq = lane >> 4, l15 = lane & 15;
    int bh = blockIdx.x;
    int b = bh >> 3, h = bh & 7;

    const short* kp = k + (size_t)bh * T_ * D_;
    const short* vp = v + (size_t)bh * T_ * D_;
    const short* qp = q + (size_t)bh * T_ * D_;

    // ---- stage K (bf16 source: straight 16B vector copies) ----
    for (int idx = tid; idx < 8 * 208; idx += 256) {
        int g = idx / 208, s = idx - g * 208;
        int kt = s >> 4, l = s & 15;
        bf16x8 val;
        if (s < 200) {
            val = *(const bf16x8*)(kp + (size_t)s * 64 + g * 8);
        } else {
            #pragma unroll
            for (int j = 0; j < 8; ++j) val[j] = 0;
        }
        *(bf16x8*)&Kf[((kt * 8 + g) * 16 + l) * 8] = val;
    }
    // ---- stage V^T (coalesced 2B gathers: lane-consecutive d) ----
    for (int idx = tid; idx < 28 * 64; idx += 256) {
        int g = idx >> 6, d = idx & 63;
        int nt = d >> 4, dl = d & 15;
        bf16x8 val;
        if (g < 25) {
            #pragma unroll
            for (int j = 0; j < 8; ++j) val[j] = vp[(g * 8 + j) * 64 + d];
        } else {
            #pragma unroll
            for (int j = 0; j < 8; ++j) val[j] = 0;
        }
        *(bf16x8*)&Vf[((nt * 28 + g) * 16 + dl) * 8] = val;
    }
    __syncthreads();

    short* pb = &Pb[wave * 512];

    for (int qt = wave; qt < NQT; qt += 4) {
        int t0 = qt * 16;
        // Q A-frags: direct 16B loads (OOB rows t>=200 read next ws buffer - never stored)
        bf16x8 qf[2];
        #pragma unroll
        for (int ks = 0; ks < 2; ++ks)
            qf[ks] = *(const bf16x8*)(qp + (size_t)(t0 + l15) * 64 + ks * 32 + qq * 8);
        // ---- S = Q K^T ----
        f32x4 sc[NQT];
        #pragma unroll
        for (int kt = 0; kt < NQT; ++kt) {
            f32x4 a = {0.f, 0.f, 0.f, 0.f};
            bf16x8 kf0 = *(const bf16x8*)&Kf[((kt * 8 + qq) * 16 + l15) * 8];
            bf16x8 kf1 = *(const bf16x8*)&Kf[((kt * 8 + 4 + qq) * 16 + l15) * 8];
            a = __builtin_amdgcn_mfma_f32_16x16x32_bf16(qf[0], kf0, a, 0, 0, 0);
            a = __builtin_amdgcn_mfma_f32_16x16x32_bf16(qf[1], kf1, a, 0, 0, 0);
            sc[kt] = a;
        }
        // ---- scale + causal mask (select: NaN-safe) ----
        #pragma unroll
        for (int kt = 0; kt < NQT; ++kt) {
            #pragma unroll
            for (int r = 0; r < 4; ++r) {
                int col = kt * 16 + l15;
                int rowg = t0 + qq * 4 + r;
                sc[kt][r] = (col <= rowg) ? sc[kt][r] * SCALE : -1e30f;
            }
        }
        // ---- softmax: row max / exp / row sum (rows live in 16 l15 lanes) ----
        float mx[4], sum[4], inv[4];
        #pragma unroll
        for (int r = 0; r < 4; ++r) {
            float m = -1e30f;
            #pragma unroll
            for (int kt = 0; kt < NQT; ++kt) m = fmaxf(m, sc[kt][r]);
            #pragma unroll
            for (int off = 1; off < 16; off <<= 1)
                m = fmaxf(m, __shfl_xor(m, off, 64));
            mx[r] = m;
        }
        #pragma unroll
        for (int r = 0; r < 4; ++r) sum[r] = 0.f;
        #pragma unroll
        for (int kt = 0; kt < NQT; ++kt) {
            #pragma unroll
            for (int r = 0; r < 4; ++r) {
                float e = __expf(sc[kt][r] - mx[r]);
                sc[kt][r] = e;
                sum[r] += e;
            }
        }
        #pragma unroll
        for (int r = 0; r < 4; ++r) {
            float s = sum[r];
            #pragma unroll
            for (int off = 1; off < 16; off <<= 1) s += __shfl_xor(s, off, 64);
            inv[r] = 1.0f / s;
        }
        // ---- O = P V, chunked P->LDS round-trip (32 s per chunk) ----
        f32x4 oa[4] = {};
        #pragma unroll
        for (int c = 0; c < 7; ++c) {
            #pragma unroll
            for (int kt2 = 0; kt2 < 2; ++kt2) {
                int kt = c * 2 + kt2;
                int g = kt2 * 2 + (l15 >> 3);
                int jj = l15 & 7;
                #pragma unroll
                for (int r = 0; r < 4; ++r) {
                    float val = (kt < NQT) ? sc[kt][r] : 0.0f;
                    pb[(g * 16 + qq * 4 + r) * 8 + jj] = f2bf(val);
                }
            }
            bf16x8 pf = *(const bf16x8*)&pb[(qq * 16 + l15) * 8];
            #pragma unroll
            for (int nt = 0; nt < 4; ++nt) {
                bf16x8 vf = *(const bf16x8*)&Vf[((nt * 28 + c * 4 + qq) * 16 + l15) * 8];
                oa[nt] = __builtin_amdgcn_mfma_f32_16x16x32_bf16(pf, vf, oa[nt], 0, 0, 0);
            }
        }
        // ---- store O (scaled by 1/l) ----
        #pragma unroll
        for (int nt = 0; nt < 4; ++nt) {
            #pragma unroll
            for (int r = 0; r < 4; ++r) {
                int t = t0 + qq * 4 + r;
                if (t < T_) {
                    int d = nt * 16 + l15;
                    o[((size_t)b * T_ + t) * E_ + h * D_ + d] =
                        __float2bfloat16(oa[nt][r] * inv[r]);
                }
            }
        }
    }
}

extern "C" void kernel_launch(void* const* d_in, const int* in_sizes, int n_in,
                              void* d_out, int out_size, void* d_ws, size_t ws_size,
                              hipStream_t stream) {
    const float* idx    = (const float*)d_in[0];
    const float* memory = (const float*)d_in[1];
    const int* src_mask  = (const int*)d_in[2];
    const int* pred_mask = (const int*)d_in[3];
    const float* sa_wq = (const float*)d_in[4];
    const float* sa_wk = (const float*)d_in[5];
    const float* sa_wv = (const float*)d_in[6];
    const float* sa_wo = (const float*)d_in[7];
    const float* sa_bo = (const float*)d_in[8];
    const float* ca_wq = (const float*)d_in[9];
    const float* ca_wk = (const float*)d_in[10];
    const float* ca_wv = (const float*)d_in[11];
    const float* ca_wo = (const float*)d_in[12];
    const float* ca_bo = (const float*)d_in[13];
    const float* f_w1  = (const float*)d_in[14];
    const float* f_b1  = (const float*)d_in[15];
    const float* f_w2  = (const float*)d_in[16];
    const float* f_b2  = (const float*)d_in[17];
    const float* ln1_g = (const float*)d_in[18];
    const float* ln1_b = (const float*)d_in[19];
    const float* ln2_g = (const float*)d_in[20];
    const float* ln2_b = (const float*)d_in[21];
    const float* ln3_g = (const float*)d_in[22];
    const float* ln3_b = (const float*)d_in[23];
    float* out = (float*)d_out;

    const size_t BTE = (size_t)B_ * T_ * E_;  // 6,553,600
    const size_t EE = (size_t)E_ * E_;        // 262,144

    char* p = (char*)d_ws;
    short* qb = (short*)p;            p += BTE * 2;   // bf16 QKV buffers, consecutive
    short* kb = (short*)p;            p += BTE * 2;
    short* vb = (short*)p;            p += BTE * 2;
    float* x1 = (float*)p;            p += BTE * 4;
    __hip_bfloat16* h_bf   = (__hip_bfloat16*)p; p += BTE * 2;
    __hip_bfloat16* o_bf   = (__hip_bfloat16*)p; p += BTE * 2;
    __hip_bfloat16* mem_bf = (__hip_bfloat16*)p; p += BTE * 2;
    __hip_bfloat16* w_qkv_s = (__hip_bfloat16*)p; p += 3 * EE * 2;  // sa q|k|v (1536,512)
    __hip_bfloat16* w_o_s   = (__hip_bfloat16*)p; p += EE * 2;
    __hip_bfloat16* w_qvk_c = (__hip_bfloat16*)p; p += 3 * EE * 2;  // ca q|v|k (1536,512)
    __hip_bfloat16* w_o_c   = (__hip_bfloat16*)p; p += EE * 2;
    __hip_bfloat16* w1T     = (__hip_bfloat16*)p; p += EE * 4 * 2;  // (2048,512)
    __hip_bfloat16* w2T     = (__hip_bfloat16*)p; p += EE * 4 * 2;  // (512,2048)
    short* ff_bf = qb;  // aliases qb..x1 region (dead by FFN)

    const int M = B_ * T_;  // 12800
    dim3 blk(256);
    dim3 g512(E_ / 128, M / 128);       // (4, 100)
    dim3 g1536(12, M / 128);            // fused q|k|v and q|v|k (1200 blocks)
    dim3 g2048(16, M / 128);            // FFN up (1600 blocks)

    // ---- prep: weight transposes (64x64 LDS-tiled) + memory convert ----
    dim3 t512(8, 8), t_w1(32, 8), t_w2(8, 32);
    wt_kernel<1><<<t512, blk, 0, stream>>>(sa_wq, w_qkv_s, E_, E_);
    wt_kernel<1><<<t512, blk, 0, stream>>>(sa_wk, w_qkv_s + EE, E_, E_);
    wt_kernel<1><<<t512, blk, 0, stream>>>(sa_wv, w_qkv_s + 2 * EE, E_, E_);
    wt_kernel<0><<<t512, blk, 0, stream>>>(sa_wo, w_o_s, E_, E_);
    wt_kernel<1><<<t512, blk, 0, stream>>>(ca_wq, w_qvk_c, E_, E_);
    wt_kernel<1><<<t512, blk, 0, stream>>>(ca_wv, w_qvk_c + EE, E_, E_);
    wt_kernel<1><<<t512, blk, 0, stream>>>(ca_wk, w_qvk_c + 2 * EE, E_, E_);
    wt_kernel<0><<<t512, blk, 0, stream>>>(ca_wo, w_o_c, E_, E_);
    wt_kernel<0><<<t_w1, blk, 0, stream>>>(f_w1, w1T, 4 * E_, E_);
    wt_kernel<0><<<t_w2, blk, 0, stream>>>(f_w2, w2T, E_, 4 * E_);
    conv_kernel<<<((int)(BTE / 4) + 255) / 256, 256, 0, stream>>>(memory, mem_bf,
                                                                  (int)BTE);

    // ---- self-attention block ----
    ln_kernel<<<M, 256, 0, stream>>>(idx, ln1_g, ln1_b, h_bf);
    // fused QKV: cols 0-511 -> qb (masked), 512-1023 -> kb (masked), 1024-1535 -> vb
    mgemm_kernel<2,0,3,0,0><<<g1536, blk, 0, stream>>>(
        (const short*)h_bf, nullptr, (const short*)w_qkv_s, nullptr, pred_mask,
        nullptr, qb, M, 3 * E_, E_, BTE);
    fattn_kernel<<<B_ * H_, 256, 0, stream>>>(qb, kb, vb, o_bf);
    mgemm_kernel<0,0,0,1,1><<<g512, blk, 0, stream>>>(
        (const short*)o_bf, nullptr, (const short*)w_o_s, sa_bo, nullptr, idx, x1,
        M, E_, E_, 0);

    // ---- cross-attention block ----
    ln_kernel<<<M, 256, 0, stream>>>(x1, ln2_g, ln2_b, h_bf);
    // fused q|v|k: cols 0-511 (A=h) -> qb, 512-1023 (A=h) -> vb,
    //              1024-1535 (A=mem, src-masked) -> kb
    mgemm_kernel<3,0,4,0,0><<<g1536, blk, 0, stream>>>(
        (const short*)h_bf, (const short*)mem_bf, (const short*)w_qvk_c, nullptr,
        src_mask, nullptr, qb, M, 3 * E_, E_, BTE);
    fattn_kernel<<<B_ * H_, 256, 0, stream>>>(qb, kb, vb, o_bf);
    mgemm_kernel<0,0,0,1,1><<<g512, blk, 0, stream>>>(
        (const short*)o_bf, nullptr, (const short*)w_o_c, ca_bo, nullptr, x1, out,
        M, E_, E_, 0);

    // ---- feed-forward block ----
    ln_kernel<<<M, 256, 0, stream>>>(out, ln3_g, ln3_b, h_bf);
    mgemm_kernel<0,1,2,0,1><<<g2048, blk, 0, stream>>>(
        (const short*)h_bf, nullptr, (const short*)w1T, f_b1, nullptr, nullptr,
        ff_bf, M, 4 * E_, E_, 0);
    mgemm_kernel<0,0,0,1,1><<<g512, blk, 0, stream>>>(
        (const short*)ff_bf, nullptr, (const short*)w2T, f_b2, nullptr, out, out,
        M, E_, 4 * E_, 0);
}